// Round 3
// baseline (1014.697 us; speedup 1.0000x reference)
//
#include <hip/hip_runtime.h>

// Problem constants (match reference setup_inputs)
constexpr int NN = 50000;        // nodes
constexpr int NE = 1600000;      // edges
constexpr int NB = 8;            // batch
constexpr int M_ROWS = NN * NB;  // 400000 flattened rows (m = b*NN + n)

typedef unsigned short ushort;
typedef unsigned int uint;
typedef unsigned char uchar;
typedef float f32x2v __attribute__((ext_vector_type(2)));
typedef float f32x4v __attribute__((ext_vector_type(4)));
typedef uint u32x4 __attribute__((ext_vector_type(4)));
typedef uint u32x2 __attribute__((ext_vector_type(2)));

__device__ __forceinline__ ushort f2bf(float f) {
  union { float f; uint u; } v;
  v.f = f;
  const uint r = v.u + 0x7fffu + ((v.u >> 16) & 1u);  // RNE
  return (ushort)(r >> 16);
}
__device__ __forceinline__ float bfhi(uint g) {
  union { uint u; float f; } v;
  v.u = g & 0xffff0000u;
  return v.f;
}
__device__ __forceinline__ float bflo(uint g) {
  union { uint u; float f; } v;
  v.u = g << 16;
  return v.f;
}

// ---- fp8 e4m3fn -> 2x f32x2 (HW cvt; exact manual fallback) ----
__device__ __forceinline__ void fp8x4_to_f32x2(uint v, f32x2v& lo, f32x2v& hi) {
#if __has_builtin(__builtin_amdgcn_cvt_pk_f32_fp8)
  lo = __builtin_amdgcn_cvt_pk_f32_fp8((int)v, false);
  hi = __builtin_amdgcn_cvt_pk_f32_fp8((int)v, true);
#else
  union { _Float16 h; ushort u; } c0, c1, c2, c3;
  c0.u = (ushort)(((v & 0x80u) << 8) | ((v & 0x7fu) << 7));
  c1.u = (ushort)(((v & 0x8000u)) | ((v & 0x7f00u) >> 1));
  c2.u = (ushort)((((v >> 16) & 0x80u) << 8) | (((v >> 16) & 0x7fu) << 7));
  c3.u = (ushort)((((v >> 24) & 0x80u) << 8) | (((v >> 24) & 0x7fu) << 7));
  lo.x = (float)c0.h * 256.0f;
  lo.y = (float)c1.h * 256.0f;
  hi.x = (float)c2.h * 256.0f;
  hi.y = (float)c3.h * 256.0f;
#endif
}
__device__ __forceinline__ uint f32_to_fp8(float x) {
#if __has_builtin(__builtin_amdgcn_cvt_pk_fp8_f32)
  return (uint)__builtin_amdgcn_cvt_pk_fp8_f32(x, x, 0, false) & 0xffu;
#else
  union { _Float16 h; ushort u; } c;
  c.h = (_Float16)(x * (1.0f / 256.0f));
  const uint h = c.u;
  uint r = h & 0x7fffu;
  r = (r + 0x3Fu + ((r >> 7) & 1u)) >> 7;  // RNE f16 -> e4m3 (scaled)
  if (r > 0x7Eu) r = 0x7Eu;                // saturate to 448
  return ((h >> 8) & 0x80u) | r;
#endif
}
// pack 4 f32 -> 4 fp8 bytes (same HW cvt as scalar path -> bit-identical)
__device__ __forceinline__ uint pack4_fp8(float a0, float a1, float a2, float a3) {
#if __has_builtin(__builtin_amdgcn_cvt_pk_fp8_f32)
  int u = __builtin_amdgcn_cvt_pk_fp8_f32(a0, a1, 0, false);
  u = __builtin_amdgcn_cvt_pk_fp8_f32(a2, a3, u, true);
  return (uint)u;
#else
  return f32_to_fp8(a0) | (f32_to_fp8(a1) << 8) | (f32_to_fp8(a2) << 16) |
         (f32_to_fp8(a3) << 24);
#endif
}

// ---------------------------------------------------------------------------
// CSR row_ptr from sorted edge_rows via per-row binary search (lower_bound).
// ---------------------------------------------------------------------------
__global__ __launch_bounds__(256) void rowptr_kernel(const int* __restrict__ rows,
                                                     int* __restrict__ row_ptr) {
  const int r = blockIdx.x * 256 + threadIdx.x;
  if (r > NN) return;
  int lo = 0, hi = NE;
  while (lo < hi) {
    const int mid = (lo + hi) >> 1;
    if (rows[mid] < r) lo = mid + 1;
    else hi = mid;
  }
  row_ptr[r] = lo;
}

// ---------------------------------------------------------------------------
// W [128][DOUT] fp32 -> Wt [DOUT][128] bf16 (tiny, once per launch).
// ---------------------------------------------------------------------------
__global__ __launch_bounds__(256) void wtrans_kernel(const float* __restrict__ W,
                                                     ushort* __restrict__ Wt,
                                                     int dout) {
  const int idx = blockIdx.x * 256 + threadIdx.x;
  if (idx >= dout * 128) return;
  const int n = idx >> 7;
  const int k = idx & 127;
  Wt[idx] = f2bf(W[k * dout + n]);
}

// ---------------------------------------------------------------------------
// Zero-LDS MFMA GEMM: S (fp8 e4m3, batch-packed) = A[M][128] @ Wt^T.
// OPERAND SWAP: acc = mfma(w_frag, a_frag, acc)  ->  C col(lane&15)=m-row,
// C rows((lane>>4)*4+reg)=4 consecutive n-cols.  Consequences:
//  * W fragments live in REGISTERS (NT*4 bf16x8 = 128 VGPR @ DOUT=128),
//    loaded once per block; no Ws LDS, no barriers.
//  * A fragments stream DIRECTLY from global (lane reads 16B of its row).
//  * Epilogue: acc[0..3] -> 4 consecutive fp8 bytes -> ONE u32 global store;
//    lanes {l,l+16,l+32,l+48} form contiguous 16B; a wave's nt-burst fills
//    whole 128B L2 lines -> write-combines. No LDS roundtrip.
// Layout correctness by symmetry with the previous verified kernel: both
// operands use identical lane addressing (row-sel=lane&15, k=(lane>>4)*8).
// Same MFMA/k-order/fp8-cvt as before -> bit-identical S.
// S layout: PACK batches share a 256 B group:
//   S[(b/PACK)*NN + n][256] with slot (b%PACK)*DOUT + col.   PACK*DOUT == 256.
// ---------------------------------------------------------------------------
template <int DOUT, bool ABF16>
__global__ __launch_bounds__(256, 2) void gemm_mfma(const void* __restrict__ Av,
                                                    const ushort* __restrict__ Wt,
                                                    uchar* __restrict__ S) {
  constexpr int PACK = 256 / DOUT;
  constexpr int NT = DOUT / 16;
  constexpr int RT = 5;  // row-tiles per block: 1250 blocks
  typedef __attribute__((ext_vector_type(8))) short bf16x8;
  typedef __attribute__((ext_vector_type(4))) float f32x4;

  const int t = threadIdx.x;
  const int w = t >> 6;
  const int l = t & 63;
  const int lr = l & 15;        // row-sel (W row n / A row m)
  const int q8 = (l >> 4) * 8;  // k-offset in elements
  const int r4 = (l >> 4) * 4;  // n-offset of acc regs in epilogue

  // ---- W fragments: register-resident, loaded once per block ----
  bf16x8 wf[NT][4];
#pragma unroll
  for (int nt = 0; nt < NT; nt++) {
    const ushort* wp = Wt + (nt * 16 + lr) * 128 + q8;
#pragma unroll
    for (int ks = 0; ks < 4; ks++)
      wf[nt][ks] = *(const bf16x8*)(wp + ks * 32);
  }

  for (int rt = 0; rt < RT; rt++) {
    const size_t m = (size_t)blockIdx.x * (64 * RT) + rt * 64 + w * 16 + lr;

    // ---- A fragments: direct global load (bf16) or load+convert (fp32) ----
    bf16x8 af[4];
    if constexpr (ABF16) {
      const ushort* A = (const ushort*)Av + m * 128 + q8;
#pragma unroll
      for (int ks = 0; ks < 4; ks++)
        af[ks] = __builtin_nontemporal_load((const bf16x8*)(A + ks * 32));
    } else {
      const float* A = (const float*)Av + m * 128 + q8;
#pragma unroll
      for (int ks = 0; ks < 4; ks++) {
        const f32x4v g0 = __builtin_nontemporal_load((const f32x4v*)(A + ks * 32));
        const f32x4v g1 =
            __builtin_nontemporal_load((const f32x4v*)(A + ks * 32 + 4));
        union { bf16x8 v; u32x4 u; } p;
        p.u.x = (uint)f2bf(g0.x) | ((uint)f2bf(g0.y) << 16);
        p.u.y = (uint)f2bf(g0.z) | ((uint)f2bf(g0.w) << 16);
        p.u.z = (uint)f2bf(g1.x) | ((uint)f2bf(g1.y) << 16);
        p.u.w = (uint)f2bf(g1.z) | ((uint)f2bf(g1.w) << 16);
        af[ks] = p.v;
      }
    }

    // ---- MFMA: swapped operands ----
    f32x4 acc[NT];
#pragma unroll
    for (int nt = 0; nt < NT; nt++) acc[nt] = (f32x4)0.f;
#pragma unroll
    for (int nt = 0; nt < NT; nt++)
#pragma unroll
      for (int ks = 0; ks < 4; ks++)
        acc[nt] =
            __builtin_amdgcn_mfma_f32_16x16x32_bf16(wf[nt][ks], af[ks], acc[nt], 0, 0, 0);

    // ---- epilogue: pack 4 consecutive n-cols -> one u32 store ----
    const int b = (int)(m / NN);
    const int n_node = (int)(m - (size_t)b * NN);
    uchar* Srow = S + ((size_t)(b / PACK) * NN + n_node) * 256 +
                  (b % PACK) * DOUT + r4;
#pragma unroll
    for (int nt = 0; nt < NT; nt++) {
      const uint p = pack4_fp8(acc[nt][0], acc[nt][1], acc[nt][2], acc[nt][3]);
      __builtin_nontemporal_store(p, (uint*)(Srow + nt * 16));
    }
  }
}

// ---------------------------------------------------------------------------
// Batch-packed SpMM over fp8 S. PACK batches per 256 B group; one wave per
// (row r, batch group). grid = (NN/4, NB/PACK), x-fastest keeps the hot
// gather slice (12.8 MB) contiguous in time.
// Per edge: ONE 256 B request (2 fully-used lines); lane loads uint = 4 fp8.
// Addressing: wave-uniform SGPR base + 32-bit voffset (c<<8 pre-scaled once
// per chunk, +lane*4 folded into one v_add). 16 gathers in flight; packed
// v_pk_fma_f32 accumulation (per-channel edge order unchanged -> bit-exact).
// RMODE: 0 none, 1 fp32, 2 bf16 resid.
// ---------------------------------------------------------------------------
template <int PACK, int RMODE, bool SIGMOID, bool OBF16>
__global__ __launch_bounds__(256) void spmm_kernel(
    const uchar* __restrict__ S, const int* __restrict__ row_ptr,
    const int* __restrict__ cols, const float* __restrict__ vals,
    const float* __restrict__ bias, const void* resid, void* out) {
  constexpr int DOUT = 256 / PACK;
  constexpr int LPB = 64 / PACK;  // lanes per batch

  const int wave = threadIdx.x >> 6;
  const int lane = threadIdx.x & 63;
  const int r = blockIdx.x * 4 + wave;  // NN % 4 == 0
  const int bg = lane / LPB;
  const int j = (lane % LPB) * 4;
  const int b = blockIdx.y * PACK + bg;
  // wave-uniform base -> SADDR global_load; per-lane part folded into voffset
  const uchar* __restrict__ Sg = S + (size_t)blockIdx.y * ((size_t)NN * 256);
  const uint lane4 = (uint)lane << 2;

  f32x2v a01 = {0.f, 0.f};
  f32x2v a23 = {0.f, 0.f};

  const int e0 = row_ptr[r];
  const int e1 = row_ptr[r + 1];

  for (int e = e0; e < e1; e += 64) {
    const int n = min(64, e1 - e);
    uint c8 = 0;
    float wv = 0.f;
    if (lane < n) {
      c8 = (uint)__builtin_nontemporal_load(cols + e + lane) << 8;  // pre-scale
      wv = __builtin_nontemporal_load(vals + e + lane);
    }
    int i = 0;
    for (; i + 16 <= n; i += 16) {
      float ww[16];
      uint gg[16];
#pragma unroll
      for (int s = 0; s < 16; s++) {
        const uint off = (uint)__shfl((int)c8, i + s) + lane4;
        ww[s] = __shfl(wv, i + s);
        gg[s] = *(const uint*)(Sg + off);
      }
#pragma unroll
      for (int s = 0; s < 16; s++) {
        f32x2v lo, hi;
        fp8x4_to_f32x2(gg[s], lo, hi);
        const f32x2v w2 = {ww[s], ww[s]};
        a01 = __builtin_elementwise_fma(w2, lo, a01);
        a23 = __builtin_elementwise_fma(w2, hi, a23);
      }
    }
    for (; i + 4 <= n; i += 4) {
      float ww[4];
      uint gg[4];
#pragma unroll
      for (int s = 0; s < 4; s++) {
        const uint off = (uint)__shfl((int)c8, i + s) + lane4;
        ww[s] = __shfl(wv, i + s);
        gg[s] = *(const uint*)(Sg + off);
      }
#pragma unroll
      for (int s = 0; s < 4; s++) {
        f32x2v lo, hi;
        fp8x4_to_f32x2(gg[s], lo, hi);
        const f32x2v w2 = {ww[s], ww[s]};
        a01 = __builtin_elementwise_fma(w2, lo, a01);
        a23 = __builtin_elementwise_fma(w2, hi, a23);
      }
    }
    for (; i < n; i++) {
      const uint off = (uint)__shfl((int)c8, i) + lane4;
      const float wi = __shfl(wv, i);
      const uint g = *(const uint*)(Sg + off);
      f32x2v lo, hi;
      fp8x4_to_f32x2(g, lo, hi);
      const f32x2v w2 = {wi, wi};
      a01 = __builtin_elementwise_fma(w2, lo, a01);
      a23 = __builtin_elementwise_fma(w2, hi, a23);
    }
  }

  float a0 = a01.x, a1 = a01.y, a2 = a23.x, a3 = a23.y;

  // epilogue: bias + residual + relu (+ sigmoid)
  const size_t orow = (size_t)(b * NN + r) * DOUT + j;
  const f32x4v bb = *(const f32x4v*)(bias + j);
  a0 += bb.x;
  a1 += bb.y;
  a2 += bb.z;
  a3 += bb.w;
  if constexpr (RMODE == 1) {
    const f32x4v res =
        __builtin_nontemporal_load((const f32x4v*)((const float*)resid + orow));
    a0 += res.x;
    a1 += res.y;
    a2 += res.z;
    a3 += res.w;
  } else if constexpr (RMODE == 2) {
    const u32x2 g =
        __builtin_nontemporal_load((const u32x2*)((const ushort*)resid + orow));
    a0 += bflo(g.x);
    a1 += bfhi(g.x);
    a2 += bflo(g.y);
    a3 += bfhi(g.y);
  }
  a0 = fmaxf(a0, 0.f);
  a1 = fmaxf(a1, 0.f);
  a2 = fmaxf(a2, 0.f);
  a3 = fmaxf(a3, 0.f);
  if constexpr (SIGMOID) {
    a0 = 1.f / (1.f + __expf(-a0));
    a1 = 1.f / (1.f + __expf(-a1));
    a2 = 1.f / (1.f + __expf(-a2));
    a3 = 1.f / (1.f + __expf(-a3));
  }
  if constexpr (OBF16) {
    u32x2 o;
    o.x = (uint)f2bf(a0) | ((uint)f2bf(a1) << 16);
    o.y = (uint)f2bf(a2) | ((uint)f2bf(a3) << 16);
    __builtin_nontemporal_store(o, (u32x2*)((ushort*)out + orow));
  } else {
    f32x4v o;
    o.x = a0;
    o.y = a1;
    o.z = a2;
    o.w = a3;
    __builtin_nontemporal_store(o, (f32x4v*)((float*)out + orow));
  }
}

// ---------------------------------------------------------------------------
// Launch. ws: row_ptr(0x40000) | Wt1(0x48000) | Wt2(0x50000) | Wt3(0x54000)
// | S fp8 packed 51.2 MB (0x60000) | H bf16 102.4 MB.  ~154 MB total.
// ---------------------------------------------------------------------------
extern "C" void kernel_launch(void* const* d_in, const int* in_sizes, int n_in,
                              void* d_out, int out_size, void* d_ws, size_t ws_size,
                              hipStream_t stream) {
  const float* x = (const float*)d_in[0];
  const int* erows = (const int*)d_in[1];
  const int* ecols = (const int*)d_in[2];
  const float* evals = (const float*)d_in[3];
  const float* W1 = (const float*)d_in[4];
  const float* b1 = (const float*)d_in[5];
  const float* W2 = (const float*)d_in[6];
  const float* b2 = (const float*)d_in[7];
  const float* W3 = (const float*)d_in[8];
  const float* b3 = (const float*)d_in[9];

  char* ws = (char*)d_ws;
  int* row_ptr = (int*)ws;
  ushort* Wt1 = (ushort*)(ws + 0x40000);
  ushort* Wt2 = (ushort*)(ws + 0x48000);
  ushort* Wt3 = (ushort*)(ws + 0x50000);
  uchar* Sf8 = (uchar*)(ws + 0x60000);
  ushort* H = (ushort*)(ws + 0x60000 + (size_t)M_ROWS * 128);

  rowptr_kernel<<<(NN + 256) / 256, 256, 0, stream>>>(erows, row_ptr);
  wtrans_kernel<<<(128 * 128) / 256, 256, 0, stream>>>(W1, Wt1, 128);
  wtrans_kernel<<<(128 * 128) / 256, 256, 0, stream>>>(W2, Wt2, 128);
  wtrans_kernel<<<(64 * 128) / 256, 256, 0, stream>>>(W3, Wt3, 64);

  const dim3 sgrid128(NN / 4, NB / 2);  // pair-packed
  const dim3 sgrid64(NN / 4, NB / 4);   // quad-packed
  constexpr int GB = M_ROWS / (64 * 5);  // 1250 blocks (RT=5)

  // Layer 1: S = x@W1 (fp8 pair-packed); H = relu(spmm(S) + b1 + x)
  gemm_mfma<128, false><<<GB, 256, 0, stream>>>(x, Wt1, Sf8);
  spmm_kernel<2, 1, false, true><<<sgrid128, 256, 0, stream>>>(
      Sf8, row_ptr, ecols, evals, b1, x, H);
  // Layer 2: S = H@W2 (fp8 pair-packed); H = relu(spmm(S) + b2 + H)
  gemm_mfma<128, true><<<GB, 256, 0, stream>>>(H, Wt2, Sf8);
  spmm_kernel<2, 2, false, true><<<sgrid128, 256, 0, stream>>>(
      Sf8, row_ptr, ecols, evals, b2, H, H);
  // Layer 3: S = H@W3 (fp8 quad-packed); out = sigmoid(relu(spmm(S) + b3))
  gemm_mfma<64, true><<<GB, 256, 0, stream>>>(H, Wt3, Sf8);
  spmm_kernel<4, 0, true, false><<<sgrid64, 256, 0, stream>>>(
      Sf8, row_ptr, ecols, evals, b3, nullptr, (float*)d_out);
}

// Round 4
// 930.442 us; speedup vs baseline: 1.0906x; 1.0906x over previous
//
#include <hip/hip_runtime.h>

// Problem constants (match reference setup_inputs)
constexpr int NN = 50000;        // nodes
constexpr int NE = 1600000;      // edges
constexpr int NB = 8;            // batch
constexpr int M_ROWS = NN * NB;  // 400000 flattened rows (m = b*NN + n)

typedef unsigned short ushort;
typedef unsigned int uint;
typedef unsigned char uchar;
typedef float f32x2v __attribute__((ext_vector_type(2)));
typedef float f32x4v __attribute__((ext_vector_type(4)));
typedef uint u32x4 __attribute__((ext_vector_type(4)));
typedef uint u32x2 __attribute__((ext_vector_type(2)));

__device__ __forceinline__ ushort f2bf(float f) {
  union { float f; uint u; } v;
  v.f = f;
  const uint r = v.u + 0x7fffu + ((v.u >> 16) & 1u);  // RNE
  return (ushort)(r >> 16);
}
__device__ __forceinline__ float bfhi(uint g) {
  union { uint u; float f; } v;
  v.u = g & 0xffff0000u;
  return v.f;
}
__device__ __forceinline__ float bflo(uint g) {
  union { uint u; float f; } v;
  v.u = g << 16;
  return v.f;
}

// ---- fp8 e4m3fn -> 2x f32x2 (HW cvt; exact manual fallback) ----
__device__ __forceinline__ void fp8x4_to_f32x2(uint v, f32x2v& lo, f32x2v& hi) {
#if __has_builtin(__builtin_amdgcn_cvt_pk_f32_fp8)
  lo = __builtin_amdgcn_cvt_pk_f32_fp8((int)v, false);
  hi = __builtin_amdgcn_cvt_pk_f32_fp8((int)v, true);
#else
  union { _Float16 h; ushort u; } c0, c1, c2, c3;
  c0.u = (ushort)(((v & 0x80u) << 8) | ((v & 0x7fu) << 7));
  c1.u = (ushort)(((v & 0x8000u)) | ((v & 0x7f00u) >> 1));
  c2.u = (ushort)((((v >> 16) & 0x80u) << 8) | (((v >> 16) & 0x7fu) << 7));
  c3.u = (ushort)((((v >> 24) & 0x80u) << 8) | (((v >> 24) & 0x7fu) << 7));
  lo.x = (float)c0.h * 256.0f;
  lo.y = (float)c1.h * 256.0f;
  hi.x = (float)c2.h * 256.0f;
  hi.y = (float)c3.h * 256.0f;
#endif
}
__device__ __forceinline__ uint f32_to_fp8(float x) {
#if __has_builtin(__builtin_amdgcn_cvt_pk_fp8_f32)
  return (uint)__builtin_amdgcn_cvt_pk_fp8_f32(x, x, 0, false) & 0xffu;
#else
  union { _Float16 h; ushort u; } c;
  c.h = (_Float16)(x * (1.0f / 256.0f));
  const uint h = c.u;
  uint r = h & 0x7fffu;
  r = (r + 0x3Fu + ((r >> 7) & 1u)) >> 7;  // RNE f16 -> e4m3 (scaled)
  if (r > 0x7Eu) r = 0x7Eu;                // saturate to 448
  return ((h >> 8) & 0x80u) | r;
#endif
}

// ---------------------------------------------------------------------------
// CSR row_ptr from sorted edge_rows via per-row binary search (lower_bound).
// ---------------------------------------------------------------------------
__global__ __launch_bounds__(256) void rowptr_kernel(const int* __restrict__ rows,
                                                     int* __restrict__ row_ptr) {
  const int r = blockIdx.x * 256 + threadIdx.x;
  if (r > NN) return;
  int lo = 0, hi = NE;
  while (lo < hi) {
    const int mid = (lo + hi) >> 1;
    if (rows[mid] < r) lo = mid + 1;
    else hi = mid;
  }
  row_ptr[r] = lo;
}

// ---------------------------------------------------------------------------
// W [128][DOUT] fp32 -> Wt [DOUT][128] bf16 (tiny, once per launch).
// ---------------------------------------------------------------------------
__global__ __launch_bounds__(256) void wtrans_kernel(const float* __restrict__ W,
                                                     ushort* __restrict__ Wt,
                                                     int dout) {
  const int idx = blockIdx.x * 256 + threadIdx.x;
  if (idx >= dout * 128) return;
  const int n = idx >> 7;
  const int k = idx & 127;
  Wt[idx] = f2bf(W[k * dout + n]);
}

// ---------------------------------------------------------------------------
// MFMA GEMM: S (fp8 e4m3, batch-packed) = A[M][128] @ Wt^T.
// A fp32 (ABF16=0) or bf16. Block = 256 thr = 4 waves.
// Ws staged in LDS ONCE per block (round-1/3 experiments: global-B or
// reg-resident-W both slower).  RT=5 row-tiles (320 rows) per block.
// S layout: PACK batches share a 256 B group:
//   S[(b/PACK)*NN + n][256] with slot (b%PACK)*DOUT + col.   PACK*DOUT == 256.
// Epilogue via byte-LDS for coalesced 16B stores.
// ---------------------------------------------------------------------------
template <int DOUT, bool ABF16>
__global__ __launch_bounds__(256) void gemm_mfma(const void* __restrict__ Av,
                                                 const ushort* __restrict__ Wt,
                                                 uchar* __restrict__ S) {
  constexpr int PACK = 256 / DOUT;
  constexpr int NT = DOUT / 16;
  constexpr int RT = 5;               // row-tiles per block (320 rows)
  constexpr int LDK = 136;            // bf16 LDS row stride
  constexpr int LB = DOUT + 16;       // byte-epilogue row stride
  typedef __attribute__((ext_vector_type(8))) short bf16x8;
  typedef __attribute__((ext_vector_type(4))) float f32x4;

  __shared__ ushort As[64 * LDK];     // reused as byte buffer in epilogue
  __shared__ ushort Ws[DOUT * LDK];

  const int t = threadIdx.x;
  const int w = t >> 6;
  const int l = t & 63;

  // ---- stage Wt: DOUT x 128 bf16 -> LDS (once per block) ----
#pragma unroll
  for (int q = 0; q < (DOUT * 128) / (8 * 256); q++) {
    const int chunk = t + q * 256;
    const int n = chunk >> 4;
    const int off = (chunk & 15) * 8;
    *(uint4*)(Ws + n * LDK + off) = *(const uint4*)(Wt + n * 128 + off);
  }

  const int mrow = w * 16 + (l & 15);
  const int q8 = (l >> 4) * 8;

  for (int rt = 0; rt < RT; rt++) {
    const size_t m0 = (size_t)blockIdx.x * (64 * RT) + (size_t)rt * 64;

    // ---- stage A tile: 64 rows x 128 -> bf16 LDS ----
    if constexpr (ABF16) {
      const ushort* A = (const ushort*)Av;
#pragma unroll
      for (int q = 0; q < 4; q++) {
        const int chunk = t + q * 256;
        const int row = chunk >> 4;
        const int off = (chunk & 15) * 8;
        *(u32x4*)(As + row * LDK + off) =
            __builtin_nontemporal_load((const u32x4*)(A + (m0 + row) * 128 + off));
      }
    } else {
      const float* A = (const float*)Av;
      const int row = t >> 2;
      const int c0 = (t & 3) * 32;
      const float* src = A + (m0 + row) * 128 + c0;
      ushort* dst = As + row * LDK + c0;
#pragma unroll
      for (int q = 0; q < 8; q++) {
        const f32x4v g = __builtin_nontemporal_load((const f32x4v*)(src + q * 4));
        u32x2 p;
        p.x = (uint)f2bf(g.x) | ((uint)f2bf(g.y) << 16);
        p.y = (uint)f2bf(g.z) | ((uint)f2bf(g.w) << 16);
        *(u32x2*)(dst + q * 4) = p;  // one ds_write_b64 instead of 4x b16
      }
    }
    __syncthreads();

    bf16x8 a[4];
    const ushort* ap = As + mrow * LDK + q8;
#pragma unroll
    for (int ks = 0; ks < 4; ks++) a[ks] = *(const bf16x8*)(ap + ks * 32);

    f32x4 acc[NT];
#pragma unroll
    for (int nt = 0; nt < NT; nt++) acc[nt] = (f32x4)0.f;

#pragma unroll
    for (int nt = 0; nt < NT; nt++) {
      const ushort* bp = Ws + (nt * 16 + (l & 15)) * LDK + q8;
#pragma unroll
      for (int ks = 0; ks < 4; ks++) {
        const bf16x8 b = *(const bf16x8*)(bp + ks * 32);
        acc[nt] =
            __builtin_amdgcn_mfma_f32_16x16x32_bf16(a[ks], b, acc[nt], 0, 0, 0);
      }
    }

    // ---- epilogue: acc -> fp8 byte-LDS -> packed 16B global stores ----
    __syncthreads();
    uchar* Ab = (uchar*)As;
    const int erow = w * 16 + (l >> 4) * 4;
    const int ecol = l & 15;
#pragma unroll
    for (int nt = 0; nt < NT; nt++)
#pragma unroll
      for (int r = 0; r < 4; r++)
        Ab[(erow + r) * LB + nt * 16 + ecol] = (uchar)f32_to_fp8(acc[nt][r]);
    __syncthreads();

#pragma unroll
    for (int q = 0; q < (64 * DOUT) / (16 * 256); q++) {
      const int chunk = t + q * 256;
      const int row = chunk / (DOUT / 16);
      const int off = (chunk % (DOUT / 16)) * 16;
      const uint4 v = *(const uint4*)(Ab + row * LB + off);
      const int m = (int)m0 + row;
      const int b = m / NN;
      const int n = m - b * NN;
      *(uint4*)(S + ((size_t)(b / PACK) * NN + n) * 256 + (b % PACK) * DOUT + off) = v;
    }
    __syncthreads();  // Ab (=As) is re-staged next iteration
  }
}

// ---------------------------------------------------------------------------
// Batch-packed SpMM over fp8 S. PACK batches per 256 B group; one wave per
// (row r, batch group). grid = (NN/4, NB/PACK), x-fastest keeps the hot
// gather slice (12.8 MB) contiguous in time.
// SCALAR edge stream: r is forced wave-uniform via readfirstlane, so
// row_ptr / cols / vals compile to SGPR s_loads — no vector preload, no
// shuffles, no ww VGPRs.  Per edge the vector side is exactly:
// 1 v_add (SGPR c8 + lane4), 1 global_load_dword, 2 cvt, 2 v_pk_fma_f32.
// gg[16] (16 VGPRs) keeps 16 gathers genuinely in flight.
// Accumulation order strictly edge-index-ascending -> bit-exact vs prior.
// RMODE: 0 none, 1 fp32, 2 bf16 resid.
// ---------------------------------------------------------------------------
template <int PACK, int RMODE, bool SIGMOID, bool OBF16>
__global__ __launch_bounds__(256) void spmm_kernel(
    const uchar* __restrict__ S, const int* __restrict__ row_ptr,
    const int* __restrict__ cols, const float* __restrict__ vals,
    const float* __restrict__ bias, const void* resid, void* out) {
  constexpr int DOUT = 256 / PACK;
  constexpr int LPB = 64 / PACK;  // lanes per batch

  const int wave = threadIdx.x >> 6;
  const int lane = threadIdx.x & 63;
  // force wave-uniformity so the edge stream scalarizes to s_loads
  const int r = __builtin_amdgcn_readfirstlane(blockIdx.x * 4 + wave);
  const int bg = lane / LPB;
  const int j = (lane % LPB) * 4;
  const int b = blockIdx.y * PACK + bg;
  const uchar* __restrict__ Sg = S + (size_t)blockIdx.y * ((size_t)NN * 256);
  const uint lane4 = (uint)lane << 2;

  f32x2v a01 = {0.f, 0.f};
  f32x2v a23 = {0.f, 0.f};

  const int e0 = __builtin_amdgcn_readfirstlane(row_ptr[r]);
  const int e1 = __builtin_amdgcn_readfirstlane(row_ptr[r + 1]);

  int e = e0;
  // ---- 16-deep uniform chunks: 16 scalar (c,w) + 16 gathers in flight ----
  for (; e + 16 <= e1; e += 16) {
    uint gg[16];
#pragma unroll
    for (int s = 0; s < 16; s++) {
      const uint c8 = ((uint)cols[e + s]) << 8;  // SGPR
      gg[s] = *(const uint*)(Sg + c8 + lane4);   // 1 v_add + load
    }
#pragma unroll
    for (int s = 0; s < 16; s++) {
      const float wi = vals[e + s];              // SGPR
      f32x2v lo, hi;
      fp8x4_to_f32x2(gg[s], lo, hi);
      const f32x2v w2 = {wi, wi};
      a01 = __builtin_elementwise_fma(w2, lo, a01);
      a23 = __builtin_elementwise_fma(w2, hi, a23);
    }
  }
  // ---- 4-deep tail chunks ----
  for (; e + 4 <= e1; e += 4) {
    uint gg[4];
#pragma unroll
    for (int s = 0; s < 4; s++) {
      const uint c8 = ((uint)cols[e + s]) << 8;
      gg[s] = *(const uint*)(Sg + c8 + lane4);
    }
#pragma unroll
    for (int s = 0; s < 4; s++) {
      const float wi = vals[e + s];
      f32x2v lo, hi;
      fp8x4_to_f32x2(gg[s], lo, hi);
      const f32x2v w2 = {wi, wi};
      a01 = __builtin_elementwise_fma(w2, lo, a01);
      a23 = __builtin_elementwise_fma(w2, hi, a23);
    }
  }
  // ---- last edges ----
  for (; e < e1; e++) {
    const uint c8 = ((uint)cols[e]) << 8;
    const float wi = vals[e];
    const uint g = *(const uint*)(Sg + c8 + lane4);
    f32x2v lo, hi;
    fp8x4_to_f32x2(g, lo, hi);
    const f32x2v w2 = {wi, wi};
    a01 = __builtin_elementwise_fma(w2, lo, a01);
    a23 = __builtin_elementwise_fma(w2, hi, a23);
  }

  float a0 = a01.x, a1 = a01.y, a2 = a23.x, a3 = a23.y;

  // epilogue: bias + residual + relu (+ sigmoid)
  const size_t orow = (size_t)(b * NN + r) * DOUT + j;
  const f32x4v bb = *(const f32x4v*)(bias + j);
  a0 += bb.x;
  a1 += bb.y;
  a2 += bb.z;
  a3 += bb.w;
  if constexpr (RMODE == 1) {
    const f32x4v res =
        __builtin_nontemporal_load((const f32x4v*)((const float*)resid + orow));
    a0 += res.x;
    a1 += res.y;
    a2 += res.z;
    a3 += res.w;
  } else if constexpr (RMODE == 2) {
    const u32x2 g =
        __builtin_nontemporal_load((const u32x2*)((const ushort*)resid + orow));
    a0 += bflo(g.x);
    a1 += bfhi(g.x);
    a2 += bflo(g.y);
    a3 += bfhi(g.y);
  }
  a0 = fmaxf(a0, 0.f);
  a1 = fmaxf(a1, 0.f);
  a2 = fmaxf(a2, 0.f);
  a3 = fmaxf(a3, 0.f);
  if constexpr (SIGMOID) {
    a0 = 1.f / (1.f + __expf(-a0));
    a1 = 1.f / (1.f + __expf(-a1));
    a2 = 1.f / (1.f + __expf(-a2));
    a3 = 1.f / (1.f + __expf(-a3));
  }
  if constexpr (OBF16) {
    u32x2 o;
    o.x = (uint)f2bf(a0) | ((uint)f2bf(a1) << 16);
    o.y = (uint)f2bf(a2) | ((uint)f2bf(a3) << 16);
    __builtin_nontemporal_store(o, (u32x2*)((ushort*)out + orow));
  } else {
    f32x4v o;
    o.x = a0;
    o.y = a1;
    o.z = a2;
    o.w = a3;
    __builtin_nontemporal_store(o, (f32x4v*)((float*)out + orow));
  }
}

// ---------------------------------------------------------------------------
// Launch. ws: row_ptr(0x40000) | Wt1(0x48000) | Wt2(0x50000) | Wt3(0x54000)
// | S fp8 packed 51.2 MB (0x60000) | H bf16 102.4 MB.  ~154 MB total.
// ---------------------------------------------------------------------------
extern "C" void kernel_launch(void* const* d_in, const int* in_sizes, int n_in,
                              void* d_out, int out_size, void* d_ws, size_t ws_size,
                              hipStream_t stream) {
  const float* x = (const float*)d_in[0];
  const int* erows = (const int*)d_in[1];
  const int* ecols = (const int*)d_in[2];
  const float* evals = (const float*)d_in[3];
  const float* W1 = (const float*)d_in[4];
  const float* b1 = (const float*)d_in[5];
  const float* W2 = (const float*)d_in[6];
  const float* b2 = (const float*)d_in[7];
  const float* W3 = (const float*)d_in[8];
  const float* b3 = (const float*)d_in[9];

  char* ws = (char*)d_ws;
  int* row_ptr = (int*)ws;
  ushort* Wt1 = (ushort*)(ws + 0x40000);
  ushort* Wt2 = (ushort*)(ws + 0x48000);
  ushort* Wt3 = (ushort*)(ws + 0x50000);
  uchar* Sf8 = (uchar*)(ws + 0x60000);
  ushort* H = (ushort*)(ws + 0x60000 + (size_t)M_ROWS * 128);

  rowptr_kernel<<<(NN + 256) / 256, 256, 0, stream>>>(erows, row_ptr);
  wtrans_kernel<<<(128 * 128) / 256, 256, 0, stream>>>(W1, Wt1, 128);
  wtrans_kernel<<<(128 * 128) / 256, 256, 0, stream>>>(W2, Wt2, 128);
  wtrans_kernel<<<(64 * 128) / 256, 256, 0, stream>>>(W3, Wt3, 64);

  const dim3 sgrid128(NN / 4, NB / 2);  // pair-packed
  const dim3 sgrid64(NN / 4, NB / 4);   // quad-packed
  constexpr int GB = M_ROWS / (64 * 5);  // 1250 blocks (RT=5)

  // Layer 1: S = x@W1 (fp8 pair-packed); H = relu(spmm(S) + b1 + x)
  gemm_mfma<128, false><<<GB, 256, 0, stream>>>(x, Wt1, Sf8);
  spmm_kernel<2, 1, false, true><<<sgrid128, 256, 0, stream>>>(
      Sf8, row_ptr, ecols, evals, b1, x, H);
  // Layer 2: S = H@W2 (fp8 pair-packed); H = relu(spmm(S) + b2 + H)
  gemm_mfma<128, true><<<GB, 256, 0, stream>>>(H, Wt2, Sf8);
  spmm_kernel<2, 2, false, true><<<sgrid128, 256, 0, stream>>>(
      Sf8, row_ptr, ecols, evals, b2, H, H);
  // Layer 3: S = H@W3 (fp8 quad-packed); out = sigmoid(relu(spmm(S) + b3))
  gemm_mfma<64, true><<<GB, 256, 0, stream>>>(H, Wt3, Sf8);
  spmm_kernel<4, 0, true, false><<<sgrid64, 256, 0, stream>>>(
      Sf8, row_ptr, ecols, evals, b3, nullptr, (float*)d_out);
}